// Round 20
// baseline (255.629 us; speedup 1.0000x reference)
//
#include <hip/hip_runtime.h>
#include <math.h>

#define HH 256
#define WW 256
#define AREA 65536
#define CIN 16
#define NS 4
#define CSUR 128
#define NEXT 144
#define NPAIR 45

typedef __attribute__((ext_vector_type(8))) _Float16 f16x8;
typedef __attribute__((ext_vector_type(2))) _Float16 f16x2;
typedef __attribute__((ext_vector_type(4))) float f32x4;

__constant__ int c_dy[8] = {-1,-1,-1, 0, 0, 1, 1, 1};
__constant__ int c_dx[8] = {-1, 0, 1,-1, 1,-1, 0, 1};

__device__ constexpr int CTI[NPAIR] = {
    0, 1,1, 2,2,2, 3,3,3,3, 4,4,4,4,4,
    5,5,5,5,5,5, 6,6,6,6,6,6,6, 7,7,7,7,7,7,7,7,
    8,8,8,8,8,8,8,8,8};
__device__ constexpr int CTJ[NPAIR] = {
    0, 0,1, 0,1,2, 0,1,2,3, 0,1,2,3,4,
    0,1,2,3,4,5, 0,1,2,3,4,5,6, 0,1,2,3,4,5,6,7,
    0,1,2,3,4,5,6,7,8};

__device__ __forceinline__ int refl(int v) {
    return v < 0 ? -v : (v > 255 ? 510 - v : v);
}

// pack 2 floats to fp16x2 (v_cvt_pkrtz_f16_f32)
__device__ __forceinline__ unsigned pkh(float a, float b) {
    auto h2 = __builtin_amdgcn_cvt_pkrtz(a, b);
    return __builtin_bit_cast(unsigned, h2);
}

__device__ __forceinline__ float fdot2(unsigned v, unsigned w, float acc) {
    return __builtin_amdgcn_fdot2(__builtin_bit_cast(f16x2, v),
                                  __builtin_bit_cast(f16x2, w), acc, false);
}

// write one fp16 pair into swizzled row: row c = 32 uints (64 px), 8 groups
// of 4 uints; group g stored at slot g ^ (c&7). halfk: 0 = px 0..31, 1 = 32..63.
__device__ __forceinline__ void wph(unsigned* __restrict__ m,
                                    int c, int pxp, int halfk, float a, float b) {
    const int sw = c & 7, gi = halfk * 4 + (pxp >> 2), e = pxp & 3;
    m[c * 32 + ((gi ^ sw) << 2) + e] = pkh(a, b);
}

// stage one round (64 pixels: row y, cols x0..x0+63) as fp16
template <bool FAST>
__device__ __forceinline__ void stage64(unsigned* __restrict__ m,
                                        const float* __restrict__ base,
                                        int y, int x0, int cin, int pxp, int d) {
    constexpr int DY[8] = {-1,-1,-1, 0, 0, 1, 1, 1};
    constexpr int DX[8] = {-1, 0, 1,-1, 1,-1, 0, 1};
    const int xA = x0 + 2 * pxp;
    const int xB = xA + 32;
    const float* rowy = base + y * WW;
    const float2 cA = *(const float2*)(rowy + xA);
    const float2 cB = *(const float2*)(rowy + xB);
    wph(m, cin, pxp, 0, cA.x, cA.y);
    wph(m, cin, pxp, 1, cB.x, cB.y);
#pragma unroll
    for (int kk = 0; kk < 8; ++kk) {
        float2 sA, sB;
        if (FAST) {
            const float* row = base + (y + DY[kk] * d) * WW;
            sA = *(const float2*)(row + xA + DX[kk] * d);
            sB = *(const float2*)(row + xB + DX[kk] * d);
        } else {
            const int ys = refl(y + DY[kk] * d);
            const float* row = base + ys * WW;
            const int off = DX[kk] * d;
            sA.x = row[refl(xA + off)];
            sA.y = row[refl(xA + 1 + off)];
            sB.x = row[refl(xB + off)];
            sB.y = row[refl(xB + 1 + off)];
        }
        const int c = 16 + kk * 16 + cin;
        wph(m, c, pxp, 0, sA.x - cA.x, sA.y - cA.y);
        wph(m, c, pxp, 1, sB.x - cB.x, sB.y - cB.y);
    }
}

// ---------------------------------------------------------------------------
// K0: pack cen f32 -> cenH fp16 cin-pairs: cenH[(b*8+c2)*AREA + pix].
// ---------------------------------------------------------------------------
__global__ __launch_bounds__(256) void k0_pack(const float* __restrict__ cen,
                                               unsigned* __restrict__ cenH) {
    const size_t i = (size_t)blockIdx.x * 256 + threadIdx.x;  // 2,097,152
    const int b = (int)(i >> 19);
    const int c2 = (int)((i >> 16) & 7);
    const int pix = (int)(i & 65535);
    const float a  = cen[((size_t)b * 16 + 2 * c2) * AREA + pix];
    const float bb = cen[((size_t)b * 16 + 2 * c2 + 1) * AREA + pix];
    cenH[i] = pkh(a, bb);
}

// ---------------------------------------------------------------------------
// K1: diff Gram via fp16 MFMA (16x16x32_f16), K=64/round, single LDS buffer
// 18.4 KB. 2 rows/chunk -> grid (128 chunks, s=4, b=4) = 2048 blocks
// (8 blocks/CU for latency hiding), 256 thr. 2 partial buffers (chunk&1).
// ---------------------------------------------------------------------------
__global__ __launch_bounds__(256) void k1_gram(const float* __restrict__ cen,
                                               float* __restrict__ part) {
    const int chunk = blockIdx.x;          // 0..127 -> 2 rows each
    const int s = blockIdx.y;
    const int b = blockIdx.z;
    const int d = 1 << s;
    const int t = threadIdx.x;
    const int lane = t & 63, wid = t >> 6;
    const int lr = lane & 15, lg = lane >> 4;
    const int cin = t >> 4, pxp = t & 15;
    const int y0 = chunk * 2;
    const float* base = cen + ((size_t)b * CIN + cin) * AREA;

    __shared__ unsigned lds[NEXT * 32];    // 18,432 B = 144 rows x 64 px fp16

    const int rA = ((lg ^ (lr & 7)) << 2);         // k-half A groups 0..3
    const int rB = (((4 + lg) ^ (lr & 7)) << 2);   // k-half B groups 4..7

    f32x4 acc[12];
#pragma unroll
    for (int i = 0; i < 12; ++i) acc[i] = (f32x4){0.f, 0.f, 0.f, 0.f};

    for (int rd = 0; rd < 8; ++rd) {
        const int y  = y0 + (rd >> 2);
        const int x0 = (rd & 3) * 64;
        if (y >= 8 && y <= 247 && x0 >= 64 && x0 <= 128)
            stage64<true>(lds, base, y, x0, cin, pxp, d);
        else
            stage64<false>(lds, base, y, x0, cin, pxp, d);
        __syncthreads();
        f16x8 fA[9], fB[9];
#pragma unroll
        for (int tt = 0; tt < 9; ++tt) {
            const int rb = (tt * 16 + lr) * 32;
            fA[tt] = __builtin_bit_cast(f16x8, *(const uint4*)(lds + rb + rA));
            fB[tt] = __builtin_bit_cast(f16x8, *(const uint4*)(lds + rb + rB));
        }
        __syncthreads();   // lgkm drained before barrier -> frags safely in regs
#pragma unroll
        for (int p = 0; p < NPAIR; ++p) {
            if ((p & 3) == wid) {
                const int i = CTI[p], j = CTJ[p], a = p >> 2;
                acc[a] = __builtin_amdgcn_mfma_f32_16x16x32_f16(fA[i], fA[j], acc[a], 0, 0, 0);
                acc[a] = __builtin_amdgcn_mfma_f32_16x16x32_f16(fB[i], fB[j], acc[a], 0, 0, 0);
            }
        }
    }

    float* tb = part + (size_t)((chunk & 1) * 16 + b * 4 + s) * 20736;
#pragma unroll
    for (int p = 0; p < NPAIR; ++p) {
        if ((p & 3) == wid) {
            const int gi0 = CTI[p] * 16 + lg * 4;
            const int gj  = CTJ[p] * 16 + lr;
            const f32x4 a = acc[p >> 2];
#pragma unroll
            for (int r = 0; r < 4; ++r)
                atomicAdd(&tb[(gi0 + r) * 144 + gj], a[r]);
        }
    }
}

// ---------------------------------------------------------------------------
// kA: fused partial-sum + A + normK + normQ. grid (s=4, b=4, z=9), 256 thr.
// ---------------------------------------------------------------------------
__global__ __launch_bounds__(256) void kA(const float* __restrict__ part,
                                          const float* __restrict__ q_w,
                                          const float* __restrict__ k_w,
                                          float* __restrict__ A,
                                          float* __restrict__ normK,
                                          float* __restrict__ normQ) {
    const int s = blockIdx.x, b = blockIdx.y, z = blockIdx.z, bs = b * 4 + s;
    const int t = threadIdx.x;
    const int i0 = z * 16;
    __shared__ float Ts[16][148];
    __shared__ float kwS[128][129];
    __shared__ float red[2][128];

    const float* p0 = part + (size_t)(0 * 16 + bs) * 20736;
    const float* p1 = part + (size_t)(1 * 16 + bs) * 20736;
    for (int e = t; e < 16 * 144; e += 256) {
        const int il = e / 144, j = e - il * 144;
        const int i = i0 + il;
        const int src = (i >= j) ? (i * 144 + j) : (j * 144 + i);
        Ts[il][j] = p0[src] + p1[src];
    }
    if (z >= 1) {
        const float* kws = k_w + (size_t)s * 16384;
        for (int e = t; e < 16384; e += 256)
            kwS[e >> 7][e & 127] = kws[e];
    }
    __syncthreads();

    if (z >= 1) {
        for (int e = t; e < 1024; e += 256) {
            const int il = e >> 6, jq = e & 63;
            const float* qr = q_w + jq * 16;
            float aa = 0.f;
#pragma unroll
            for (int c = 0; c < 16; ++c) aa = fmaf(qr[c], Ts[il][c], aa);
            A[((size_t)bs * 64 + jq) * 128 + (i0 - 16 + il)] = aa;
        }
        const int ck = t & 127, half = t >> 7;
        float accil[16];
#pragma unroll
        for (int il = 0; il < 16; ++il) accil[il] = 0.f;
        for (int j = half * 64; j < half * 64 + 64; ++j) {
            const float kj = kwS[ck][j];
#pragma unroll
            for (int il = 0; il < 16; ++il)
                accil[il] = fmaf(kj, Ts[il][16 + j], accil[il]);
        }
        float prt = 0.f;
#pragma unroll
        for (int il = 0; il < 16; ++il)
            prt = fmaf(kwS[ck][i0 - 16 + il], accil[il], prt);
        red[half][ck] = prt;
        __syncthreads();
        if (t < 128)
            atomicAdd(&normK[(size_t)bs * 128 + t], red[0][t] + red[1][t]);
    } else if (s == 0 && t < 64) {
        float nq = 0.f;
#pragma unroll
        for (int c1 = 0; c1 < 16; ++c1) {
            float ra = 0.f;
#pragma unroll
            for (int c2 = 0; c2 < 16; ++c2)
                ra = fmaf(q_w[t * 16 + c2], Ts[c1][c2], ra);
            nq = fmaf(q_w[t * 16 + c1], ra, nq);
        }
        normQ[b * 64 + t] = nq;
    }
}

// ---------------------------------------------------------------------------
// kB (r15-proven): scores -> instance norm -> softmax -> wEff.
// grid (a=4, b=4), 256 threads.
// ---------------------------------------------------------------------------
__global__ __launch_bounds__(256) void kB(const float* __restrict__ k_w,
                                          const float* __restrict__ v_w,
                                          const float* __restrict__ A,
                                          const float* __restrict__ normK,
                                          const float* __restrict__ normQ,
                                          float* __restrict__ wEff) {
    const int a = blockIdx.x, b = blockIdx.y;
    const int t = threadIdx.x;
    __shared__ float AS[4][16][128];
    __shared__ float kv[4][32][132];
    __shared__ float sc[2048];
    __shared__ float red[256];
    __shared__ float rowred[256];
    __shared__ float rowmax[16], rowsum[16];
    __shared__ float s_mu, s_rs;

    for (int idx = t; idx < 8192; idx += 256) {
        const int sk = idx >> 11, rr = (idx >> 7) & 15, cp = idx & 127;
        const int jq = (rr & 3) * 16 + 4 * a + (rr >> 2);
        AS[sk][rr][cp] = A[((size_t)(b * 4 + sk) * 64 + jq) * 128 + cp];
    }
    for (int idx = t; idx < 16384; idx += 256) {
        const int sk = idx >> 12, ckl = (idx >> 7) & 31, cp = idx & 127;
        kv[sk][ckl][cp] = k_w[((size_t)sk * 128 + 32 * a + ckl) * 128 + cp];
    }
    __syncthreads();
    for (int e = t; e < 2048; e += 256) {
        const int r = e >> 7, dd = e & 127;
        const int sk = dd & 3, ckl = dd >> 2;
        const float4* Ar = (const float4*)(&AS[sk][r][0]);
        const float4* kr = (const float4*)(&kv[sk][ckl][0]);
        float4 pv = {0.f, 0.f, 0.f, 0.f};
#pragma unroll 8
        for (int jj = 0; jj < 32; ++jj) {
            const float4 h = Ar[jj], k4 = kr[jj];
            pv.x = fmaf(h.x, k4.x, pv.x);
            pv.y = fmaf(h.y, k4.y, pv.y);
            pv.z = fmaf(h.z, k4.z, pv.z);
            pv.w = fmaf(h.w, k4.w, pv.w);
        }
        const float dot = pv.x + pv.y + pv.z + pv.w;
        const int jq = (r & 3) * 16 + 4 * a + (r >> 2);
        const float qn = fmaxf(sqrtf(fmaxf(normQ[b * 64 + jq], 0.f)), 1e-12f);
        const float kn = fmaxf(sqrtf(fmaxf(normK[(size_t)(b * 4 + sk) * 128 + 32 * a + ckl], 0.f)), 1e-12f);
        sc[e] = dot / (qn * kn * 256.0f);
    }
    __syncthreads();
    // reload kv with v_w (all score reads of kv done; barriers below fence it)
    for (int idx = t; idx < 16384; idx += 256) {
        const int sk = idx >> 12, m = (idx >> 7) & 31, cp = idx & 127;
        kv[sk][m][cp] = v_w[((size_t)sk * 128 + 32 * a + m) * 128 + cp];
    }
    {
        float p = 0.f;
        for (int e = t; e < 2048; e += 256) p += sc[e];
        red[t] = p; __syncthreads();
        for (int off = 128; off > 0; off >>= 1) {
            if (t < off) red[t] += red[t + off];
            __syncthreads();
        }
        if (t == 0) s_mu = red[0] * (1.f / 2048.f);
        __syncthreads();
    }
    {
        const float mu = s_mu;
        float p = 0.f;
        for (int e = t; e < 2048; e += 256) { const float z = sc[e] - mu; p += z * z; }
        red[t] = p; __syncthreads();
        for (int off = 128; off > 0; off >>= 1) {
            if (t < off) red[t] += red[t + off];
            __syncthreads();
        }
        if (t == 0) s_rs = rsqrtf(red[0] * (1.f / 2048.f) + 1e-5f);
        __syncthreads();
    }
    const float mu = s_mu, rs = s_rs;
    const int r = t >> 4, l = t & 15;
    {
        float m = -1e30f;
#pragma unroll
        for (int j = 0; j < 8; ++j) {
            const float z = (sc[r * 128 + l + j * 16] - mu) * rs;
            m = fmaxf(m, z);
        }
        rowred[t] = m; __syncthreads();
        if (l == 0) {
            float m2 = rowred[r * 16];
            for (int j = 1; j < 16; ++j) m2 = fmaxf(m2, rowred[r * 16 + j]);
            rowmax[r] = m2;
        }
        __syncthreads();
    }
    {
        float p = 0.f;
#pragma unroll
        for (int j = 0; j < 8; ++j) {
            const float z = (sc[r * 128 + l + j * 16] - mu) * rs;
            p += expf(z - rowmax[r]);
        }
        rowred[t] = p; __syncthreads();
        if (l == 0) {
            float p2 = 0.f;
            for (int j = 0; j < 16; ++j) p2 += rowred[r * 16 + j];
            rowsum[r] = p2;
        }
        __syncthreads();
    }
    {
        float vals[8];
#pragma unroll
        for (int j = 0; j < 8; ++j) {
            const float z = (sc[r * 128 + l + j * 16] - mu) * rs;
            vals[j] = expf(z - rowmax[r]) / rowsum[r];
        }
        __syncthreads();
#pragma unroll
        for (int j = 0; j < 8; ++j) sc[r * 128 + l + j * 16] = vals[j];
        __syncthreads();
    }
    for (int e = t; e < 8192; e += 256) {
        const int sk = e >> 11, r2 = (e >> 7) & 15, cp = e & 127;
        float w = 0.f;
#pragma unroll
        for (int m = 0; m < 32; ++m)
            w = fmaf(sc[r2 * 128 + 4 * m + sk], kv[sk][m][cp], w);
        wEff[((size_t)(b * 4 + sk) * 64 + (a * 16 + r2)) * 128 + cp] = w;
    }
}

// ---------------------------------------------------------------------------
// K2c: packed fp16 weights wPk[bs][k][c2][o] + wcG[b][cin][o] center sums.
// grid (s=4, b=4), 256 threads.
// ---------------------------------------------------------------------------
__global__ __launch_bounds__(256) void k2c(const float* __restrict__ out_w,
                                           const float* __restrict__ bn_gamma,
                                           const float* __restrict__ bn_var,
                                           const float* __restrict__ wEff,
                                           unsigned* __restrict__ wPk,
                                           float* __restrict__ wcG) {
    const int s = blockIdx.x, b = blockIdx.y;
    const int t = threadIdx.x;
    __shared__ float we[64][128];
    __shared__ float wfS[16][128];
    for (int idx = t; idx < 8192; idx += 256) {
        const int j = idx >> 7, cp = idx & 127;
        we[j][cp] = wEff[((size_t)(b * 4 + s) * 64 + j) * 128 + cp];
    }
    __syncthreads();
    for (int e = t; e < 2048; e += 256) {
        const int o = e >> 7, cp = e & 127;
        float w = 0.f;
#pragma unroll 16
        for (int j = 0; j < 64; ++j)
            w = fmaf(out_w[o * 64 + j], we[j][cp], w);
        const float scale = bn_gamma[o] * rsqrtf(bn_var[o] + 1e-5f);
        wfS[o][cp] = w * scale;
    }
    __syncthreads();
    for (int e = t; e < 1024; e += 256) {
        const int k8 = e >> 7, c2 = (e >> 4) & 7, o = e & 15;
        wPk[((size_t)(b * 4 + s) * 8 + k8) * 128 + c2 * 16 + o] =
            pkh(wfS[o][k8 * 16 + 2 * c2], wfS[o][k8 * 16 + 2 * c2 + 1]);
    }
    {
        const int cin = t >> 4, o = t & 15;
        float p = 0.f;
#pragma unroll
        for (int kk = 0; kk < 8; ++kk) p += wfS[o][kk * 16 + cin];
        atomicAdd(&wcG[(size_t)b * 256 + cin * 16 + o], p);
    }
}

// ---------------------------------------------------------------------------
// K3: out = relu( sum taps + bias ), taps via fp16 dot2 (2 cin per instr).
// grid (256 rows, b=4), 256 threads, 1 px/thread.
// ---------------------------------------------------------------------------
__global__ __launch_bounds__(256) void k3_out(const float* __restrict__ cen,
                                              const unsigned* __restrict__ cenH,
                                              const unsigned* __restrict__ wPk,
                                              const float* __restrict__ wcG,
                                              const float* __restrict__ bn_gamma,
                                              const float* __restrict__ bn_beta,
                                              const float* __restrict__ bn_mean,
                                              const float* __restrict__ bn_var,
                                              float* __restrict__ out) {
    const int y = blockIdx.x;
    const int b = blockIdx.y;
    const int x = threadIdx.x;
    const unsigned* hb = cenH + (size_t)b * 8 * AREA;

    float acc[16];
#pragma unroll
    for (int o = 0; o < 16; ++o) acc[o] = 0.f;

    for (int s = 0; s < NS; ++s) {
        const int d = 1 << s;
        for (int k = 0; k < 8; ++k) {
            const int ry = refl(y + c_dy[k] * d);
            const int rx = refl(x + c_dx[k] * d);
            const unsigned* prow = hb + ry * WW + rx;
            const int woff = __builtin_amdgcn_readfirstlane(
                ((b * 4 + s) * 8 + k) * 128);
            const unsigned* wbase = wPk + woff;
#pragma unroll
            for (int c2 = 0; c2 < 8; ++c2) {
                const unsigned v = prow[c2 * AREA];
                const uint4* w4 = reinterpret_cast<const uint4*>(wbase + c2 * 16);
#pragma unroll
                for (int oq = 0; oq < 4; ++oq) {
                    const uint4 wv = w4[oq];
                    acc[oq*4+0] = fdot2(v, wv.x, acc[oq*4+0]);
                    acc[oq*4+1] = fdot2(v, wv.y, acc[oq*4+1]);
                    acc[oq*4+2] = fdot2(v, wv.z, acc[oq*4+2]);
                    acc[oq*4+3] = fdot2(v, wv.w, acc[oq*4+3]);
                }
            }
        }
    }
    // center subtraction (f32 path, proven)
    {
        const float* crow = cen + (size_t)b * CIN * AREA + y * WW;
        const int coff = __builtin_amdgcn_readfirstlane(b * 256);
        const float* wcb = wcG + coff;
#pragma unroll
        for (int cin = 0; cin < 16; ++cin) {
            const float v = crow[cin * AREA + x];
            const float4* w4 = reinterpret_cast<const float4*>(wcb + cin * 16);
#pragma unroll
            for (int oq = 0; oq < 4; ++oq) {
                const float4 w = w4[oq];
                acc[oq*4+0] = fmaf(-w.x, v, acc[oq*4+0]);
                acc[oq*4+1] = fmaf(-w.y, v, acc[oq*4+1]);
                acc[oq*4+2] = fmaf(-w.z, v, acc[oq*4+2]);
                acc[oq*4+3] = fmaf(-w.w, v, acc[oq*4+3]);
            }
        }
    }
#pragma unroll
    for (int o = 0; o < 16; ++o) {
        const float scale = bn_gamma[o] * rsqrtf(bn_var[o] + 1e-5f);
        const float bias  = bn_beta[o] - bn_mean[o] * scale;
        out[((size_t)(b * 16 + o) * HH + y) * WW + x] = fmaxf(acc[o] + bias, 0.f);
    }
}

// ---------------------------------------------------------------------------
extern "C" void kernel_launch(void* const* d_in, const int* in_sizes, int n_in,
                              void* d_out, int out_size, void* d_ws, size_t ws_size,
                              hipStream_t stream) {
    const float* cen      = (const float*)d_in[0];
    const float* q_w      = (const float*)d_in[1];
    const float* k_w      = (const float*)d_in[2];
    const float* v_w      = (const float*)d_in[3];
    const float* out_w    = (const float*)d_in[4];
    const float* bn_gamma = (const float*)d_in[5];
    const float* bn_beta  = (const float*)d_in[6];
    const float* bn_mean  = (const float*)d_in[7];
    const float* bn_var   = (const float*)d_in[8];
    float* out = (float*)d_out;

    char* ws = (char*)d_ws;
    const size_t PART_BYTES  = (size_t)2 * 16 * 20736 * 4;   // 2,654,208
    const size_t NK_BYTES    = (size_t)16 * 128 * 4;         //     8,192
    const size_t WC_BYTES    = (size_t)4 * 256 * 4;          //     4,096
    const size_t A_BYTES     = (size_t)16 * 64 * 128 * 4;    //   524,288
    const size_t NQ_BYTES    = (size_t)4 * 64 * 4;           //     1,024
    const size_t WEFF_BYTES  = (size_t)16 * 64 * 128 * 4;    //   524,288
    const size_t WPK_BYTES   = (size_t)16 * 8 * 128 * 4;     //    65,536
    // cenH: 4*8*65536 uints = 8,388,608 bytes

    float*    part  = (float*)(ws);
    float*    normK = (float*)(ws + PART_BYTES);
    float*    wcG   = (float*)(ws + PART_BYTES + NK_BYTES);
    float*    A     = (float*)(ws + PART_BYTES + NK_BYTES + WC_BYTES);
    float*    normQ = (float*)(ws + PART_BYTES + NK_BYTES + WC_BYTES + A_BYTES);
    float*    wEff  = (float*)(ws + PART_BYTES + NK_BYTES + WC_BYTES + A_BYTES + NQ_BYTES);
    unsigned* wPk   = (unsigned*)(ws + PART_BYTES + NK_BYTES + WC_BYTES + A_BYTES + NQ_BYTES + WEFF_BYTES);
    unsigned* cenH  = (unsigned*)(ws + PART_BYTES + NK_BYTES + WC_BYTES + A_BYTES + NQ_BYTES + WEFF_BYTES + WPK_BYTES);

    (void)hipMemsetAsync(part, 0, PART_BYTES + NK_BYTES + WC_BYTES, stream);
    k0_pack<<<dim3(8192), 256, 0, stream>>>(cen, cenH);
    k1_gram<<<dim3(128, 4, 4), 256, 0, stream>>>(cen, part);
    kA<<<dim3(4, 4, 9), 256, 0, stream>>>(part, q_w, k_w, A, normK, normQ);
    kB<<<dim3(4, 4), 256, 0, stream>>>(k_w, v_w, A, normK, normQ, wEff);
    k2c<<<dim3(4, 4), 256, 0, stream>>>(out_w, bn_gamma, bn_var, wEff, wPk, wcG);
    k3_out<<<dim3(256, 4), 256, 0, stream>>>(cen, cenH, wPk, wcG, bn_gamma,
                                             bn_beta, bn_mean, bn_var, out);
}

// Round 21
// 236.824 us; speedup vs baseline: 1.0794x; 1.0794x over previous
//
#include <hip/hip_runtime.h>
#include <math.h>

#define HH 256
#define WW 256
#define AREA 65536
#define CIN 16
#define NS 4
#define CSUR 128
#define NEXT 144
#define NPAIR 45

typedef __attribute__((ext_vector_type(8))) _Float16 f16x8;
typedef __attribute__((ext_vector_type(2))) _Float16 f16x2;
typedef __attribute__((ext_vector_type(4))) float f32x4;

__constant__ int c_dy[8] = {-1,-1,-1, 0, 0, 1, 1, 1};
__constant__ int c_dx[8] = {-1, 0, 1,-1, 1,-1, 0, 1};

__device__ constexpr int CTI[NPAIR] = {
    0, 1,1, 2,2,2, 3,3,3,3, 4,4,4,4,4,
    5,5,5,5,5,5, 6,6,6,6,6,6,6, 7,7,7,7,7,7,7,7,
    8,8,8,8,8,8,8,8,8};
__device__ constexpr int CTJ[NPAIR] = {
    0, 0,1, 0,1,2, 0,1,2,3, 0,1,2,3,4,
    0,1,2,3,4,5, 0,1,2,3,4,5,6, 0,1,2,3,4,5,6,7,
    0,1,2,3,4,5,6,7,8};

__device__ __forceinline__ int refl(int v) {
    return v < 0 ? -v : (v > 255 ? 510 - v : v);
}

// pack 2 floats to fp16x2 (v_cvt_pkrtz_f16_f32)
__device__ __forceinline__ unsigned pkh(float a, float b) {
    auto h2 = __builtin_amdgcn_cvt_pkrtz(a, b);
    return __builtin_bit_cast(unsigned, h2);
}

__device__ __forceinline__ float fdot2(unsigned v, unsigned w, float acc) {
    return __builtin_amdgcn_fdot2(__builtin_bit_cast(f16x2, v),
                                  __builtin_bit_cast(f16x2, w), acc, false);
}

// write one fp16 pair into swizzled row: row c = 32 uints (64 px), 8 groups
// of 4 uints; group g stored at slot g ^ (c&7). halfk: 0 = px 0..31, 1 = 32..63.
__device__ __forceinline__ void wph(unsigned* __restrict__ m,
                                    int c, int pxp, int halfk, float a, float b) {
    const int sw = c & 7, gi = halfk * 4 + (pxp >> 2), e = pxp & 3;
    m[c * 32 + ((gi ^ sw) << 2) + e] = pkh(a, b);
}

// stage one round (64 pixels: row y, cols x0..x0+63) as fp16
template <bool FAST>
__device__ __forceinline__ void stage64(unsigned* __restrict__ m,
                                        const float* __restrict__ base,
                                        int y, int x0, int cin, int pxp, int d) {
    constexpr int DY[8] = {-1,-1,-1, 0, 0, 1, 1, 1};
    constexpr int DX[8] = {-1, 0, 1,-1, 1,-1, 0, 1};
    const int xA = x0 + 2 * pxp;
    const int xB = xA + 32;
    const float* rowy = base + y * WW;
    const float2 cA = *(const float2*)(rowy + xA);
    const float2 cB = *(const float2*)(rowy + xB);
    wph(m, cin, pxp, 0, cA.x, cA.y);
    wph(m, cin, pxp, 1, cB.x, cB.y);
#pragma unroll
    for (int kk = 0; kk < 8; ++kk) {
        float2 sA, sB;
        if (FAST) {
            const float* row = base + (y + DY[kk] * d) * WW;
            sA = *(const float2*)(row + xA + DX[kk] * d);
            sB = *(const float2*)(row + xB + DX[kk] * d);
        } else {
            const int ys = refl(y + DY[kk] * d);
            const float* row = base + ys * WW;
            const int off = DX[kk] * d;
            sA.x = row[refl(xA + off)];
            sA.y = row[refl(xA + 1 + off)];
            sB.x = row[refl(xB + off)];
            sB.y = row[refl(xB + 1 + off)];
        }
        const int c = 16 + kk * 16 + cin;
        wph(m, c, pxp, 0, sA.x - cA.x, sA.y - cA.y);
        wph(m, c, pxp, 1, sB.x - cB.x, sB.y - cB.y);
    }
}

// ---------------------------------------------------------------------------
// K0: pack cen f32 -> cenH fp16 cin-pairs: cenH[(b*8+c2)*AREA + pix].
// ---------------------------------------------------------------------------
__global__ __launch_bounds__(256) void k0_pack(const float* __restrict__ cen,
                                               unsigned* __restrict__ cenH) {
    const size_t i = (size_t)blockIdx.x * 256 + threadIdx.x;  // 2,097,152
    const int b = (int)(i >> 19);
    const int c2 = (int)((i >> 16) & 7);
    const int pix = (int)(i & 65535);
    const float a  = cen[((size_t)b * 16 + 2 * c2) * AREA + pix];
    const float bb = cen[((size_t)b * 16 + 2 * c2 + 1) * AREA + pix];
    cenH[i] = pkh(a, bb);
}

// ---------------------------------------------------------------------------
// K1 (r19-proven): diff Gram via fp16 MFMA (16x16x32_f16), K=64/round, single
// LDS buffer 18.4 KB. grid (64 chunks x 4 rows, s=4, b=4) = 1024 blocks,
// 256 thr. 2 partial buffers (chunk&1).
// ---------------------------------------------------------------------------
__global__ __launch_bounds__(256) void k1_gram(const float* __restrict__ cen,
                                               float* __restrict__ part) {
    const int chunk = blockIdx.x;          // 0..63 -> 4 rows each
    const int s = blockIdx.y;
    const int b = blockIdx.z;
    const int d = 1 << s;
    const int t = threadIdx.x;
    const int lane = t & 63, wid = t >> 6;
    const int lr = lane & 15, lg = lane >> 4;
    const int cin = t >> 4, pxp = t & 15;
    const int y0 = chunk * 4;
    const float* base = cen + ((size_t)b * CIN + cin) * AREA;

    __shared__ unsigned lds[NEXT * 32];    // 18,432 B = 144 rows x 64 px fp16

    const int rA = ((lg ^ (lr & 7)) << 2);         // k-half A groups 0..3
    const int rB = (((4 + lg) ^ (lr & 7)) << 2);   // k-half B groups 4..7

    f32x4 acc[12];
#pragma unroll
    for (int i = 0; i < 12; ++i) acc[i] = (f32x4){0.f, 0.f, 0.f, 0.f};

    for (int rd = 0; rd < 16; ++rd) {
        const int y  = y0 + (rd >> 2);
        const int x0 = (rd & 3) * 64;
        if (y >= 8 && y <= 247 && x0 >= 64 && x0 <= 128)
            stage64<true>(lds, base, y, x0, cin, pxp, d);
        else
            stage64<false>(lds, base, y, x0, cin, pxp, d);
        __syncthreads();
        f16x8 fA[9], fB[9];
#pragma unroll
        for (int tt = 0; tt < 9; ++tt) {
            const int rb = (tt * 16 + lr) * 32;
            fA[tt] = __builtin_bit_cast(f16x8, *(const uint4*)(lds + rb + rA));
            fB[tt] = __builtin_bit_cast(f16x8, *(const uint4*)(lds + rb + rB));
        }
        __syncthreads();   // lgkm drained before barrier -> frags safely in regs
#pragma unroll
        for (int p = 0; p < NPAIR; ++p) {
            if ((p & 3) == wid) {
                const int i = CTI[p], j = CTJ[p], a = p >> 2;
                acc[a] = __builtin_amdgcn_mfma_f32_16x16x32_f16(fA[i], fA[j], acc[a], 0, 0, 0);
                acc[a] = __builtin_amdgcn_mfma_f32_16x16x32_f16(fB[i], fB[j], acc[a], 0, 0, 0);
            }
        }
    }

    float* tb = part + (size_t)((chunk & 1) * 16 + b * 4 + s) * 20736;
#pragma unroll
    for (int p = 0; p < NPAIR; ++p) {
        if ((p & 3) == wid) {
            const int gi0 = CTI[p] * 16 + lg * 4;
            const int gj  = CTJ[p] * 16 + lr;
            const f32x4 a = acc[p >> 2];
#pragma unroll
            for (int r = 0; r < 4; ++r)
                atomicAdd(&tb[(gi0 + r) * 144 + gj], a[r]);
        }
    }
}

// ---------------------------------------------------------------------------
// kA: fused partial-sum + A + normK + normQ. grid (s=4, b=4, z=9), 256 thr.
// ---------------------------------------------------------------------------
__global__ __launch_bounds__(256) void kA(const float* __restrict__ part,
                                          const float* __restrict__ q_w,
                                          const float* __restrict__ k_w,
                                          float* __restrict__ A,
                                          float* __restrict__ normK,
                                          float* __restrict__ normQ) {
    const int s = blockIdx.x, b = blockIdx.y, z = blockIdx.z, bs = b * 4 + s;
    const int t = threadIdx.x;
    const int i0 = z * 16;
    __shared__ float Ts[16][148];
    __shared__ float kwS[128][129];
    __shared__ float red[2][128];

    const float* p0 = part + (size_t)(0 * 16 + bs) * 20736;
    const float* p1 = part + (size_t)(1 * 16 + bs) * 20736;
    for (int e = t; e < 16 * 144; e += 256) {
        const int il = e / 144, j = e - il * 144;
        const int i = i0 + il;
        const int src = (i >= j) ? (i * 144 + j) : (j * 144 + i);
        Ts[il][j] = p0[src] + p1[src];
    }
    if (z >= 1) {
        const float* kws = k_w + (size_t)s * 16384;
        for (int e = t; e < 16384; e += 256)
            kwS[e >> 7][e & 127] = kws[e];
    }
    __syncthreads();

    if (z >= 1) {
        for (int e = t; e < 1024; e += 256) {
            const int il = e >> 6, jq = e & 63;
            const float* qr = q_w + jq * 16;
            float aa = 0.f;
#pragma unroll
            for (int c = 0; c < 16; ++c) aa = fmaf(qr[c], Ts[il][c], aa);
            A[((size_t)bs * 64 + jq) * 128 + (i0 - 16 + il)] = aa;
        }
        const int ck = t & 127, half = t >> 7;
        float accil[16];
#pragma unroll
        for (int il = 0; il < 16; ++il) accil[il] = 0.f;
        for (int j = half * 64; j < half * 64 + 64; ++j) {
            const float kj = kwS[ck][j];
#pragma unroll
            for (int il = 0; il < 16; ++il)
                accil[il] = fmaf(kj, Ts[il][16 + j], accil[il]);
        }
        float prt = 0.f;
#pragma unroll
        for (int il = 0; il < 16; ++il)
            prt = fmaf(kwS[ck][i0 - 16 + il], accil[il], prt);
        red[half][ck] = prt;
        __syncthreads();
        if (t < 128)
            atomicAdd(&normK[(size_t)bs * 128 + t], red[0][t] + red[1][t]);
    } else if (s == 0 && t < 64) {
        float nq = 0.f;
#pragma unroll
        for (int c1 = 0; c1 < 16; ++c1) {
            float ra = 0.f;
#pragma unroll
            for (int c2 = 0; c2 < 16; ++c2)
                ra = fmaf(q_w[t * 16 + c2], Ts[c1][c2], ra);
            nq = fmaf(q_w[t * 16 + c1], ra, nq);
        }
        normQ[b * 64 + t] = nq;
    }
}

// ---------------------------------------------------------------------------
// kB (r15-proven): scores -> instance norm -> softmax -> wEff.
// grid (a=4, b=4), 256 threads.
// ---------------------------------------------------------------------------
__global__ __launch_bounds__(256) void kB(const float* __restrict__ k_w,
                                          const float* __restrict__ v_w,
                                          const float* __restrict__ A,
                                          const float* __restrict__ normK,
                                          const float* __restrict__ normQ,
                                          float* __restrict__ wEff) {
    const int a = blockIdx.x, b = blockIdx.y;
    const int t = threadIdx.x;
    __shared__ float AS[4][16][128];
    __shared__ float kv[4][32][132];
    __shared__ float sc[2048];
    __shared__ float red[256];
    __shared__ float rowred[256];
    __shared__ float rowmax[16], rowsum[16];
    __shared__ float s_mu, s_rs;

    for (int idx = t; idx < 8192; idx += 256) {
        const int sk = idx >> 11, rr = (idx >> 7) & 15, cp = idx & 127;
        const int jq = (rr & 3) * 16 + 4 * a + (rr >> 2);
        AS[sk][rr][cp] = A[((size_t)(b * 4 + sk) * 64 + jq) * 128 + cp];
    }
    for (int idx = t; idx < 16384; idx += 256) {
        const int sk = idx >> 12, ckl = (idx >> 7) & 31, cp = idx & 127;
        kv[sk][ckl][cp] = k_w[((size_t)sk * 128 + 32 * a + ckl) * 128 + cp];
    }
    __syncthreads();
    for (int e = t; e < 2048; e += 256) {
        const int r = e >> 7, dd = e & 127;
        const int sk = dd & 3, ckl = dd >> 2;
        const float4* Ar = (const float4*)(&AS[sk][r][0]);
        const float4* kr = (const float4*)(&kv[sk][ckl][0]);
        float4 pv = {0.f, 0.f, 0.f, 0.f};
#pragma unroll 8
        for (int jj = 0; jj < 32; ++jj) {
            const float4 h = Ar[jj], k4 = kr[jj];
            pv.x = fmaf(h.x, k4.x, pv.x);
            pv.y = fmaf(h.y, k4.y, pv.y);
            pv.z = fmaf(h.z, k4.z, pv.z);
            pv.w = fmaf(h.w, k4.w, pv.w);
        }
        const float dot = pv.x + pv.y + pv.z + pv.w;
        const int jq = (r & 3) * 16 + 4 * a + (r >> 2);
        const float qn = fmaxf(sqrtf(fmaxf(normQ[b * 64 + jq], 0.f)), 1e-12f);
        const float kn = fmaxf(sqrtf(fmaxf(normK[(size_t)(b * 4 + sk) * 128 + 32 * a + ckl], 0.f)), 1e-12f);
        sc[e] = dot / (qn * kn * 256.0f);
    }
    __syncthreads();
    // reload kv with v_w (all score reads of kv done; barriers below fence it)
    for (int idx = t; idx < 16384; idx += 256) {
        const int sk = idx >> 12, m = (idx >> 7) & 31, cp = idx & 127;
        kv[sk][m][cp] = v_w[((size_t)sk * 128 + 32 * a + m) * 128 + cp];
    }
    {
        float p = 0.f;
        for (int e = t; e < 2048; e += 256) p += sc[e];
        red[t] = p; __syncthreads();
        for (int off = 128; off > 0; off >>= 1) {
            if (t < off) red[t] += red[t + off];
            __syncthreads();
        }
        if (t == 0) s_mu = red[0] * (1.f / 2048.f);
        __syncthreads();
    }
    {
        const float mu = s_mu;
        float p = 0.f;
        for (int e = t; e < 2048; e += 256) { const float z = sc[e] - mu; p += z * z; }
        red[t] = p; __syncthreads();
        for (int off = 128; off > 0; off >>= 1) {
            if (t < off) red[t] += red[t + off];
            __syncthreads();
        }
        if (t == 0) s_rs = rsqrtf(red[0] * (1.f / 2048.f) + 1e-5f);
        __syncthreads();
    }
    const float mu = s_mu, rs = s_rs;
    const int r = t >> 4, l = t & 15;
    {
        float m = -1e30f;
#pragma unroll
        for (int j = 0; j < 8; ++j) {
            const float z = (sc[r * 128 + l + j * 16] - mu) * rs;
            m = fmaxf(m, z);
        }
        rowred[t] = m; __syncthreads();
        if (l == 0) {
            float m2 = rowred[r * 16];
            for (int j = 1; j < 16; ++j) m2 = fmaxf(m2, rowred[r * 16 + j]);
            rowmax[r] = m2;
        }
        __syncthreads();
    }
    {
        float p = 0.f;
#pragma unroll
        for (int j = 0; j < 8; ++j) {
            const float z = (sc[r * 128 + l + j * 16] - mu) * rs;
            p += expf(z - rowmax[r]);
        }
        rowred[t] = p; __syncthreads();
        if (l == 0) {
            float p2 = 0.f;
            for (int j = 0; j < 16; ++j) p2 += rowred[r * 16 + j];
            rowsum[r] = p2;
        }
        __syncthreads();
    }
    {
        float vals[8];
#pragma unroll
        for (int j = 0; j < 8; ++j) {
            const float z = (sc[r * 128 + l + j * 16] - mu) * rs;
            vals[j] = expf(z - rowmax[r]) / rowsum[r];
        }
        __syncthreads();
#pragma unroll
        for (int j = 0; j < 8; ++j) sc[r * 128 + l + j * 16] = vals[j];
        __syncthreads();
    }
    for (int e = t; e < 8192; e += 256) {
        const int sk = e >> 11, r2 = (e >> 7) & 15, cp = e & 127;
        float w = 0.f;
#pragma unroll
        for (int m = 0; m < 32; ++m)
            w = fmaf(sc[r2 * 128 + 4 * m + sk], kv[sk][m][cp], w);
        wEff[((size_t)(b * 4 + sk) * 64 + (a * 16 + r2)) * 128 + cp] = w;
    }
}

// ---------------------------------------------------------------------------
// K2c: packed fp16 weights wPk[bs][k][c2][o] + wcG[b][cin][o] center sums.
// grid (s=4, b=4), 256 threads.
// ---------------------------------------------------------------------------
__global__ __launch_bounds__(256) void k2c(const float* __restrict__ out_w,
                                           const float* __restrict__ bn_gamma,
                                           const float* __restrict__ bn_var,
                                           const float* __restrict__ wEff,
                                           unsigned* __restrict__ wPk,
                                           float* __restrict__ wcG) {
    const int s = blockIdx.x, b = blockIdx.y;
    const int t = threadIdx.x;
    __shared__ float we[64][128];
    __shared__ float wfS[16][128];
    for (int idx = t; idx < 8192; idx += 256) {
        const int j = idx >> 7, cp = idx & 127;
        we[j][cp] = wEff[((size_t)(b * 4 + s) * 64 + j) * 128 + cp];
    }
    __syncthreads();
    for (int e = t; e < 2048; e += 256) {
        const int o = e >> 7, cp = e & 127;
        float w = 0.f;
#pragma unroll 16
        for (int j = 0; j < 64; ++j)
            w = fmaf(out_w[o * 64 + j], we[j][cp], w);
        const float scale = bn_gamma[o] * rsqrtf(bn_var[o] + 1e-5f);
        wfS[o][cp] = w * scale;
    }
    __syncthreads();
    for (int e = t; e < 1024; e += 256) {
        const int k8 = e >> 7, c2 = (e >> 4) & 7, o = e & 15;
        wPk[((size_t)(b * 4 + s) * 8 + k8) * 128 + c2 * 16 + o] =
            pkh(wfS[o][k8 * 16 + 2 * c2], wfS[o][k8 * 16 + 2 * c2 + 1]);
    }
    {
        const int cin = t >> 4, o = t & 15;
        float p = 0.f;
#pragma unroll
        for (int kk = 0; kk < 8; ++kk) p += wfS[o][kk * 16 + cin];
        atomicAdd(&wcG[(size_t)b * 256 + cin * 16 + o], p);
    }
}

// ---------------------------------------------------------------------------
// K3: out = relu( sum taps + bias ), taps via fp16 dot2 (2 cin per instr).
// grid (256 rows, b=4), 256 threads, 1 px/thread.
// ---------------------------------------------------------------------------
__global__ __launch_bounds__(256) void k3_out(const float* __restrict__ cen,
                                              const unsigned* __restrict__ cenH,
                                              const unsigned* __restrict__ wPk,
                                              const float* __restrict__ wcG,
                                              const float* __restrict__ bn_gamma,
                                              const float* __restrict__ bn_beta,
                                              const float* __restrict__ bn_mean,
                                              const float* __restrict__ bn_var,
                                              float* __restrict__ out) {
    const int y = blockIdx.x;
    const int b = blockIdx.y;
    const int x = threadIdx.x;
    const unsigned* hb = cenH + (size_t)b * 8 * AREA;

    float acc[16];
#pragma unroll
    for (int o = 0; o < 16; ++o) acc[o] = 0.f;

    for (int s = 0; s < NS; ++s) {
        const int d = 1 << s;
        for (int k = 0; k < 8; ++k) {
            const int ry = refl(y + c_dy[k] * d);
            const int rx = refl(x + c_dx[k] * d);
            const unsigned* prow = hb + ry * WW + rx;
            const int woff = __builtin_amdgcn_readfirstlane(
                ((b * 4 + s) * 8 + k) * 128);
            const unsigned* wbase = wPk + woff;
#pragma unroll
            for (int c2 = 0; c2 < 8; ++c2) {
                const unsigned v = prow[c2 * AREA];
                const uint4* w4 = reinterpret_cast<const uint4*>(wbase + c2 * 16);
#pragma unroll
                for (int oq = 0; oq < 4; ++oq) {
                    const uint4 wv = w4[oq];
                    acc[oq*4+0] = fdot2(v, wv.x, acc[oq*4+0]);
                    acc[oq*4+1] = fdot2(v, wv.y, acc[oq*4+1]);
                    acc[oq*4+2] = fdot2(v, wv.z, acc[oq*4+2]);
                    acc[oq*4+3] = fdot2(v, wv.w, acc[oq*4+3]);
                }
            }
        }
    }
    // center subtraction (f32 path, proven)
    {
        const float* crow = cen + (size_t)b * CIN * AREA + y * WW;
        const int coff = __builtin_amdgcn_readfirstlane(b * 256);
        const float* wcb = wcG + coff;
#pragma unroll
        for (int cin = 0; cin < 16; ++cin) {
            const float v = crow[cin * AREA + x];
            const float4* w4 = reinterpret_cast<const float4*>(wcb + cin * 16);
#pragma unroll
            for (int oq = 0; oq < 4; ++oq) {
                const float4 w = w4[oq];
                acc[oq*4+0] = fmaf(-w.x, v, acc[oq*4+0]);
                acc[oq*4+1] = fmaf(-w.y, v, acc[oq*4+1]);
                acc[oq*4+2] = fmaf(-w.z, v, acc[oq*4+2]);
                acc[oq*4+3] = fmaf(-w.w, v, acc[oq*4+3]);
            }
        }
    }
#pragma unroll
    for (int o = 0; o < 16; ++o) {
        const float scale = bn_gamma[o] * rsqrtf(bn_var[o] + 1e-5f);
        const float bias  = bn_beta[o] - bn_mean[o] * scale;
        out[((size_t)(b * 16 + o) * HH + y) * WW + x] = fmaxf(acc[o] + bias, 0.f);
    }
}

// ---------------------------------------------------------------------------
extern "C" void kernel_launch(void* const* d_in, const int* in_sizes, int n_in,
                              void* d_out, int out_size, void* d_ws, size_t ws_size,
                              hipStream_t stream) {
    const float* cen      = (const float*)d_in[0];
    const float* q_w      = (const float*)d_in[1];
    const float* k_w      = (const float*)d_in[2];
    const float* v_w      = (const float*)d_in[3];
    const float* out_w    = (const float*)d_in[4];
    const float* bn_gamma = (const float*)d_in[5];
    const float* bn_beta  = (const float*)d_in[6];
    const float* bn_mean  = (const float*)d_in[7];
    const float* bn_var   = (const float*)d_in[8];
    float* out = (float*)d_out;

    char* ws = (char*)d_ws;
    const size_t PART_BYTES  = (size_t)2 * 16 * 20736 * 4;   // 2,654,208
    const size_t NK_BYTES    = (size_t)16 * 128 * 4;         //     8,192
    const size_t WC_BYTES    = (size_t)4 * 256 * 4;          //     4,096
    const size_t A_BYTES     = (size_t)16 * 64 * 128 * 4;    //   524,288
    const size_t NQ_BYTES    = (size_t)4 * 64 * 4;           //     1,024
    const size_t WEFF_BYTES  = (size_t)16 * 64 * 128 * 4;    //   524,288
    const size_t WPK_BYTES   = (size_t)16 * 8 * 128 * 4;     //    65,536
    // cenH: 4*8*65536 uints = 8,388,608 bytes

    float*    part  = (float*)(ws);
    float*    normK = (float*)(ws + PART_BYTES);
    float*    wcG   = (float*)(ws + PART_BYTES + NK_BYTES);
    float*    A     = (float*)(ws + PART_BYTES + NK_BYTES + WC_BYTES);
    float*    normQ = (float*)(ws + PART_BYTES + NK_BYTES + WC_BYTES + A_BYTES);
    float*    wEff  = (float*)(ws + PART_BYTES + NK_BYTES + WC_BYTES + A_BYTES + NQ_BYTES);
    unsigned* wPk   = (unsigned*)(ws + PART_BYTES + NK_BYTES + WC_BYTES + A_BYTES + NQ_BYTES + WEFF_BYTES);
    unsigned* cenH  = (unsigned*)(ws + PART_BYTES + NK_BYTES + WC_BYTES + A_BYTES + NQ_BYTES + WEFF_BYTES + WPK_BYTES);

    (void)hipMemsetAsync(part, 0, PART_BYTES + NK_BYTES + WC_BYTES, stream);
    k0_pack<<<dim3(8192), 256, 0, stream>>>(cen, cenH);
    k1_gram<<<dim3(64, 4, 4), 256, 0, stream>>>(cen, part);
    kA<<<dim3(4, 4, 9), 256, 0, stream>>>(part, q_w, k_w, A, normK, normQ);
    kB<<<dim3(4, 4), 256, 0, stream>>>(k_w, v_w, A, normK, normQ, wEff);
    k2c<<<dim3(4, 4), 256, 0, stream>>>(out_w, bn_gamma, bn_var, wEff, wPk, wcG);
    k3_out<<<dim3(256, 4), 256, 0, stream>>>(cen, cenH, wPk, wcG, bn_gamma,
                                             bn_beta, bn_mean, bn_var, out);
}